// Round 6
// baseline (192.837 us; speedup 1.0000x reference)
//
#include <hip/hip_runtime.h>

typedef short bf16x8 __attribute__((ext_vector_type(8)));
typedef float floatx4 __attribute__((ext_vector_type(4)));
typedef unsigned short ushort4v __attribute__((ext_vector_type(4)));
typedef unsigned int uint4v __attribute__((ext_vector_type(4)));

#define HW 3136
#define NB 16
#define LSTR 35   // LDS row stride in uints (32 ch-pairs + 3 pad: 2-way banks = free)
#define WS 100    // attn LDS stride (floats) per pixel

// ---- bf16 bit helpers (RNE) ----
__device__ __forceinline__ unsigned short f2bf(float f) {
    unsigned int u = __float_as_uint(f);
    unsigned int r = (u + 0x7FFFu + ((u >> 16) & 1u)) >> 16;
    return (unsigned short)r;
}
__device__ __forceinline__ float bf2f(unsigned short u) {
    return __uint_as_float(((unsigned int)u) << 16);
}
__device__ __forceinline__ void unp8(uint4 u, float* o) {
    o[0] = bf2f((unsigned short)(u.x & 0xFFFFu)); o[1] = bf2f((unsigned short)(u.x >> 16));
    o[2] = bf2f((unsigned short)(u.y & 0xFFFFu)); o[3] = bf2f((unsigned short)(u.y >> 16));
    o[4] = bf2f((unsigned short)(u.z & 0xFFFFu)); o[5] = bf2f((unsigned short)(u.z >> 16));
    o[6] = bf2f((unsigned short)(u.w & 0xFFFFu)); o[7] = bf2f((unsigned short)(u.w >> 16));
}
__device__ __forceinline__ float ldp(const void* p, int i, int isb) {
    return isb ? bf2f(((const unsigned short*)p)[i]) : ((const float*)p)[i];
}

// ---- on-device dtype detection (bn1_var in [1.0,1.5]) ----
__device__ __forceinline__ int detect_bf16(const void* varp, int* sflag) {
    if (threadIdx.x == 0) {
        const unsigned short* p = (const unsigned short*)varp;
        int ok = 1;
        for (int i = 0; i < 64; ++i) {
            unsigned short v = p[2 * i];
            if (v < 0x3F80u || v > 0x3FC0u) { ok = 0; break; }
        }
        *sflag = ok;
    }
    __syncthreads();
    return *sflag;
}

// ---------------------------------------------------------------------------
// proj: yT[n][px][r] = sum_c Wcat[r][c] * x[n][c][px]  (pixel-major bf16 out)
// Block 128 = 2 waves = 32 px x 96 rows. K staged 64-ch at a time into LDS as
// transposed [px][ch-pair] uints (all global reads dwordx4). A-frags direct
// from global (6KB/step slice, L1-hot), pipelined one sub-step ahead.
// ---------------------------------------------------------------------------
template <int ISB>
__device__ __forceinline__ void stage_load(const void* x, size_t xrow, int kb,
                                           int sc2, int spx, unsigned int (&o)[8])
{
    if (ISB) {
        const unsigned short* p = (const unsigned short*)x + xrow + (size_t)(kb + 2 * sc2) * HW + spx;
        uint4 e = *(const uint4*)p;
        uint4 d = *(const uint4*)(p + HW);
        o[0] = (e.x & 0xFFFFu) | (d.x << 16);
        o[1] = (e.x >> 16)     | (d.x & 0xFFFF0000u);
        o[2] = (e.y & 0xFFFFu) | (d.y << 16);
        o[3] = (e.y >> 16)     | (d.y & 0xFFFF0000u);
        o[4] = (e.z & 0xFFFFu) | (d.z << 16);
        o[5] = (e.z >> 16)     | (d.z & 0xFFFF0000u);
        o[6] = (e.w & 0xFFFFu) | (d.w << 16);
        o[7] = (e.w >> 16)     | (d.w & 0xFFFF0000u);
    } else {
        const float* p = (const float*)x + xrow + (size_t)(kb + 2 * sc2) * HW + spx;
        floatx4 e0 = *(const floatx4*)p,        e1 = *(const floatx4*)(p + 4);
        floatx4 d0 = *(const floatx4*)(p + HW), d1 = *(const floatx4*)(p + HW + 4);
        #pragma unroll
        for (int i = 0; i < 4; ++i) o[i]     = (unsigned int)f2bf(e0[i]) | ((unsigned int)f2bf(d0[i]) << 16);
        #pragma unroll
        for (int i = 0; i < 4; ++i) o[4 + i] = (unsigned int)f2bf(e1[i]) | ((unsigned int)f2bf(d1[i]) << 16);
    }
}

template <int ISB>
__device__ __forceinline__ bf16x8 loadA(const void* wp, int row, int cb)
{
    if (ISB) return *(const bf16x8*)((const unsigned short*)wp + row * 256 + cb);
    const float* f = (const float*)wp + row * 256 + cb;
    bf16x8 a;
    #pragma unroll
    for (int j = 0; j < 8; ++j) a[j] = (short)f2bf(f[j]);
    return a;
}

template <int ISB>
__device__ void proj_body(const void* x, const void* w1, const void* w2, const void* w3,
                          unsigned int* buf, unsigned short* y,
                          int n, int px0, int wv, int col, int quad, int sc2, int spx)
{
    const size_t xrow = (size_t)n * 256 * HW + px0;
    const void* wp[6] = {w1, w2, w3, w3, w3, w3};
    const int   ro[6] = {0, 0, 0, 16, 32, 48};

    floatx4 acc[6] = {};
    unsigned int st[8];
    stage_load<ISB>(x, xrow, 0, sc2, spx, st);
    #pragma unroll
    for (int i = 0; i < 8; ++i) buf[(spx + i) * LSTR + sc2] = st[i];

    bf16x8 Ac[6];
    #pragma unroll
    for (int r = 0; r < 6; ++r) Ac[r] = loadA<ISB>(wp[r], ro[r] + col, quad * 8);

    const unsigned int* brow = &buf[(wv * 16 + col) * LSTR];

    #pragma unroll
    for (int ko = 0; ko < 4; ++ko) {
        __syncthreads();                              // staged writes visible
        unsigned int nx[8];
        if (ko < 3) stage_load<ISB>(x, xrow, 64 * (ko + 1), sc2, spx, nx);
        #pragma unroll
        for (int s = 0; s < 2; ++s) {
            const int ss = ko * 2 + s;
            const int ib = s * 16 + quad * 4;
            uint4v bu;
            bu.x = brow[ib]; bu.y = brow[ib + 1]; bu.z = brow[ib + 2]; bu.w = brow[ib + 3];
            bf16x8 B = __builtin_bit_cast(bf16x8, bu);
            bf16x8 An[6];
            if (ss < 7) {
                #pragma unroll
                for (int r = 0; r < 6; ++r)
                    An[r] = loadA<ISB>(wp[r], ro[r] + col, (ss + 1) * 32 + quad * 8);
            }
            #pragma unroll
            for (int r = 0; r < 6; ++r)
                acc[r] = __builtin_amdgcn_mfma_f32_16x16x32_bf16(Ac[r], B, acc[r], 0, 0, 0);
            if (ss < 7) {
                #pragma unroll
                for (int r = 0; r < 6; ++r) Ac[r] = An[r];
            }
        }
        __syncthreads();                              // reads done before rewrite
        if (ko < 3) {
            #pragma unroll
            for (int i = 0; i < 8; ++i) buf[(spx + i) * LSTR + sc2] = nx[i];
        }
    }

    // D: row(W) = quad*4+g of tile r, col(px) = col
    unsigned short* yb = y + ((size_t)n * HW + px0 + wv * 16 + col) * 96 + quad * 4;
    #pragma unroll
    for (int r = 0; r < 6; ++r) {
        ushort4v pk;
        #pragma unroll
        for (int g = 0; g < 4; ++g) pk[g] = f2bf(acc[r][g]);
        *(ushort4v*)(yb + r * 16) = pk;
    }
}

__global__ __launch_bounds__(128, 4) void proj_kernel(
    const void* __restrict__ x,
    const void* __restrict__ w1, const void* __restrict__ w2,
    const void* __restrict__ w3,
    const void* __restrict__ b1v,
    unsigned short* __restrict__ y)
{
    __shared__ unsigned int buf[32 * LSTR];
    __shared__ int sflag;
    const int isb = detect_bf16(b1v, &sflag);

    const int tid = threadIdx.x;
    const int gid = blockIdx.x;
    const int n   = gid / 98;
    const int pt  = gid - n * 98;
    const int px0 = pt * 32;
    const int wv  = tid >> 6, lane = tid & 63;
    const int col = lane & 15, quad = lane >> 4;
    const int sc2 = tid >> 2;          // 0..31 ch-pair
    const int spx = (tid & 3) * 8;     // px group

    if (isb) proj_body<1>(x, w1, w2, w3, buf, y, n, px0, wv, col, quad, sc2, spx);
    else     proj_body<0>(x, w1, w2, w3, buf, y, n, px0, wv, col, quad, sc2, spx);
}

// ---------------------------------------------------------------------------
// Fused attention: block = 576 threads (9 waves) = 64 pixels.
// Phase 1: wave j, lane p -> pre-softmax h2[8] -> LDS.
// Phase 2: softmax over j. Phase 3: weighted neighbor aggregation.
// ---------------------------------------------------------------------------
__global__ __launch_bounds__(576) void attn_kernel(
    const unsigned short* __restrict__ yT,
    const void* __restrict__ cpw, const void* __restrict__ cw1,
    const void* __restrict__ cw2,
    const void* __restrict__ b1g, const void* __restrict__ b1b,
    const void* __restrict__ b1m, const void* __restrict__ b1v,
    const void* __restrict__ b2g, const void* __restrict__ b2b,
    const void* __restrict__ b2m, const void* __restrict__ b2v,
    void* __restrict__ out)
{
    __shared__ float wsm[64 * WS];
    __shared__ float w1f[288], w2f[128], cpf[4];
    __shared__ int sflag;
    const int isb = detect_bf16(b1v, &sflag);
    const int tid = threadIdx.x;
    for (int i = tid; i < 288; i += 576) w1f[i] = ldp(cw1, i, isb);
    for (int i = tid; i < 128; i += 576) w2f[i] = ldp(cw2, i, isb);
    if (tid < 4) cpf[tid] = ldp(cpw, tid, isb);
    __syncthreads();

    const int blk = blockIdx.x;
    const int n   = blk / 49;
    const int l0  = (blk - n * 49) * 64;

    // ---- phase 1 ----
    {
        const int j = tid >> 6;            // 0..8, wave-uniform
        const int p = tid & 63;
        const int l = l0 + p;
        const int h = l / 56, w = l - h * 56;
        const int dy = j / 3 - 1, dx = j - (j / 3) * 3 - 1;
        int hh = h + dy; hh = (hh < 0) ? -hh : ((hh > 55) ? 110 - hh : hh);
        int ww = w + dx; ww = (ww < 0) ? -ww : ((ww > 55) ? 110 - ww : ww);
        const int nbr = hh * 56 + ww;

        const float a1 = ldp(b1g, l, isb) * rsqrtf(ldp(b1v, l, isb) + 1e-3f);
        const float c1 = ldp(b1b, l, isb) - ldp(b1m, l, isb) * a1;
        const float a2 = ldp(b2g, l, isb) * rsqrtf(ldp(b2v, l, isb) + 1e-3f);
        const float c2 = ldp(b2b, l, isb) - ldp(b2m, l, isb) * a2;

        const unsigned short* y1p = yT + ((size_t)n * HW + l) * 96;
        const unsigned short* y2p = yT + ((size_t)n * HW + nbr) * 96 + 16;
        float y1f[16], y2f[16];
        unp8(*(const uint4*)y1p, y1f);       unp8(*(const uint4*)(y1p + 8), y1f + 8);
        unp8(*(const uint4*)y2p, y2f);       unp8(*(const uint4*)(y2p + 8), y2f + 8);

        float rel[18];
        #pragma unroll
        for (int c = 0; c < 16; ++c)
            rel[c] = fmaxf(fmaf(y1f[c] - y2f[c], a1, c1), 0.f);
        const float dlw = (float)(w - ww) * (2.0f / 55.0f);
        const float dlh = (float)(h - hh) * (2.0f / 55.0f);
        rel[16] = fmaxf(fmaf(cpf[0] * dlw + cpf[1] * dlh, a1, c1), 0.f);
        rel[17] = fmaxf(fmaf(cpf[2] * dlw + cpf[3] * dlh, a1, c1), 0.f);

        float h1[16];
        #pragma unroll
        for (int o = 0; o < 16; ++o) {
            float s = 0.f;
            #pragma unroll
            for (int c = 0; c < 18; ++c)
                s = fmaf(w1f[o * 18 + c], rel[c], s);
            h1[o] = fmaxf(fmaf(s, a2, c2), 0.f);
        }
        float h2[8];
        #pragma unroll
        for (int o2 = 0; o2 < 8; ++o2) {
            float s = 0.f;
            #pragma unroll
            for (int o = 0; o < 16; ++o)
                s = fmaf(w2f[o2 * 16 + o], h1[o], s);
            h2[o2] = s;
        }
        float* wpt = &wsm[p * WS + j * 8];
        *(floatx4*)wpt       = *(floatx4*)&h2[0];
        *(floatx4*)(wpt + 4) = *(floatx4*)&h2[4];
    }
    __syncthreads();

    // ---- phase 2: softmax over j ----
    if (tid < 512) {
        const int c = tid & 7, p = tid >> 3;
        float v[9];
        #pragma unroll
        for (int j = 0; j < 9; ++j) v[j] = wsm[p * WS + j * 8 + c];
        float m = v[0];
        #pragma unroll
        for (int j = 1; j < 9; ++j) m = fmaxf(m, v[j]);
        float s = 0.f;
        #pragma unroll
        for (int j = 0; j < 9; ++j) { v[j] = __expf(v[j] - m); s += v[j]; }
        const float inv = 1.f / s;
        #pragma unroll
        for (int j = 0; j < 9; ++j) wsm[p * WS + j * 8 + c] = v[j] * inv;
    }
    __syncthreads();

    // ---- phase 3: aggregation ----
    if (tid < 512) {
        const int p  = tid & 63;
        const int k8 = tid >> 6;
        const int l = l0 + p;
        const int h = l / 56, w = l - h * 56;
        int nbr[9];
        #pragma unroll
        for (int dy = 0; dy < 3; ++dy)
            #pragma unroll
            for (int dx = 0; dx < 3; ++dx) {
                int hh = h + dy - 1; hh = (hh < 0) ? -hh : ((hh > 55) ? 110 - hh : hh);
                int ww = w + dx - 1; ww = (ww < 0) ? -ww : ((ww > 55) ? 110 - ww : ww);
                nbr[dy * 3 + dx] = hh * 56 + ww;
            }
        const unsigned short* y3b = yT + (size_t)n * HW * 96 + 32 + k8 * 8;
        float acc8[8];
        #pragma unroll
        for (int k = 0; k < 8; ++k) acc8[k] = 0.f;
        #pragma unroll
        for (int j = 0; j < 9; ++j) {
            uint4 u = *(const uint4*)(y3b + (size_t)nbr[j] * 96);
            float yv[8];
            unp8(u, yv);
            const float* wpt = &wsm[p * WS + j * 8];
            #pragma unroll
            for (int k = 0; k < 8; ++k)
                acc8[k] = fmaf(wpt[k], yv[k], acc8[k]);
        }
        const size_t obase = ((size_t)n * 64 + k8 * 8) * HW + l;
        #pragma unroll
        for (int k = 0; k < 8; ++k) {
            if (isb) ((unsigned short*)out)[obase + (size_t)k * HW] = f2bf(acc8[k]);
            else     ((float*)out)[obase + (size_t)k * HW]          = acc8[k];
        }
    }
}

extern "C" void kernel_launch(void* const* d_in, const int* in_sizes, int n_in,
                              void* d_out, int out_size, void* d_ws, size_t ws_size,
                              hipStream_t stream)
{
    unsigned short* y = (unsigned short*)d_ws;   // 16*3136*96*2 = 9,633,792 B

    proj_kernel<<<dim3(1568), dim3(128), 0, stream>>>(
        d_in[0], d_in[1], d_in[2], d_in[3], d_in[10], y);

    attn_kernel<<<dim3(784), dim3(576), 0, stream>>>(
        y, d_in[4], d_in[5], d_in[6],
        d_in[7], d_in[8], d_in[9], d_in[10],
        d_in[11], d_in[12], d_in[13], d_in[14], d_out);
}

// Round 7
// 155.923 us; speedup vs baseline: 1.2367x; 1.2367x over previous
//
#include <hip/hip_runtime.h>

typedef short bf16x8 __attribute__((ext_vector_type(8)));
typedef float floatx4 __attribute__((ext_vector_type(4)));
typedef unsigned short ushort4v __attribute__((ext_vector_type(4)));
typedef unsigned int uintx4 __attribute__((ext_vector_type(4)));

#define HW 3136
#define WS 100   // attn LDS stride (floats) per pixel

// prep layout (floats)
#define P_CP   0
#define P_W1   4      // 288
#define P_W2   292    // 128
#define P_FLAG 420
#define P_BN   424    // a1[HW], c1[HW], a2[HW], c2[HW]
#define PREP_FLOATS (424 + 4 * HW)

// ---- bf16 bit helpers (RNE) ----
__device__ __forceinline__ unsigned short f2bf(float f) {
    unsigned int u = __float_as_uint(f);
    unsigned int r = (u + 0x7FFFu + ((u >> 16) & 1u)) >> 16;
    return (unsigned short)r;
}
__device__ __forceinline__ float bf2f(unsigned short u) {
    return __uint_as_float(((unsigned int)u) << 16);
}
__device__ __forceinline__ void unp8(uint4 u, float* o) {
    o[0] = bf2f((unsigned short)(u.x & 0xFFFFu)); o[1] = bf2f((unsigned short)(u.x >> 16));
    o[2] = bf2f((unsigned short)(u.y & 0xFFFFu)); o[3] = bf2f((unsigned short)(u.y >> 16));
    o[4] = bf2f((unsigned short)(u.z & 0xFFFFu)); o[5] = bf2f((unsigned short)(u.z >> 16));
    o[6] = bf2f((unsigned short)(u.w & 0xFFFFu)); o[7] = bf2f((unsigned short)(u.w >> 16));
}
__device__ __forceinline__ float ldp(const void* p, int i, int isb) {
    return isb ? bf2f(((const unsigned short*)p)[i]) : ((const float*)p)[i];
}

// ---- on-device dtype detection (bn1_var in [1.0,1.5]) ----
__device__ __forceinline__ int detect_bf16(const void* varp, int* sflag) {
    if (threadIdx.x == 0) {
        const unsigned short* p = (const unsigned short*)varp;
        int ok = 1;
        for (int i = 0; i < 64; ++i) {
            unsigned short v = p[2 * i];
            if (v < 0x3F80u || v > 0x3FC0u) { ok = 0; break; }
        }
        *sflag = ok;
    }
    __syncthreads();
    return *sflag;
}

// ---------------------------------------------------------------------------
// proj: wave = 128 px x 16 rows. Lane col owns px 8*col..8*col+7, so ONE
// dwordx4 per channel (16 B/lane, 4 KB contiguous per instr) feeds all 8
// px-tiles. Block 192 = 3 waves = 48 rows; grid = 16n x 2 row-halves x 25
// px-blocks = 800. 2-deep pipeline, no LDS staging, no spills (~125 regs).
// Outputs: y12[n][px][32ch] and y3a[n][k8][px][8ch] (attn-coalesced).
// ---------------------------------------------------------------------------
struct Stage { unsigned int b[32]; bf16x8 a; };

template <int ISB>
__device__ __forceinline__ void ldstage(const void* x, size_t xb,
                                        const void* wp, int arow, int ch, Stage& s)
{
    if (ISB) {
        const unsigned short* p = (const unsigned short*)x + xb + (size_t)ch * HW;
        #pragma unroll
        for (int j = 0; j < 8; ++j)
            *(uint4*)&s.b[4 * j] = *(const uint4*)(p + (size_t)j * HW);
        s.a = *(const bf16x8*)((const unsigned short*)wp + arow * 256 + ch);
    } else {
        const float* p = (const float*)x + xb + (size_t)ch * HW;
        #pragma unroll
        for (int j = 0; j < 8; ++j) {
            floatx4 f0 = *(const floatx4*)(p + (size_t)j * HW);
            floatx4 f1 = *(const floatx4*)(p + (size_t)j * HW + 4);
            s.b[4 * j + 0] = (unsigned)f2bf(f0[0]) | ((unsigned)f2bf(f0[1]) << 16);
            s.b[4 * j + 1] = (unsigned)f2bf(f0[2]) | ((unsigned)f2bf(f0[3]) << 16);
            s.b[4 * j + 2] = (unsigned)f2bf(f1[0]) | ((unsigned)f2bf(f1[1]) << 16);
            s.b[4 * j + 3] = (unsigned)f2bf(f1[2]) | ((unsigned)f2bf(f1[3]) << 16);
        }
        const float* fp = (const float*)wp + arow * 256 + ch;
        bf16x8 a;
        #pragma unroll
        for (int j = 0; j < 8; ++j) a[j] = (short)f2bf(fp[j]);
        s.a = a;
    }
}

__device__ __forceinline__ void domfma(const Stage& s, floatx4 (&acc)[8])
{
    #pragma unroll
    for (int t = 0; t < 8; ++t) {
        const int wi = t >> 1;
        uintx4 uv;
        #pragma unroll
        for (int d = 0; d < 4; ++d) {
            const unsigned lo = s.b[4 * (2 * d) + wi];
            const unsigned hi = s.b[4 * (2 * d + 1) + wi];
            const unsigned v = (t & 1) ? ((lo >> 16) | (hi & 0xFFFF0000u))
                                       : ((lo & 0xFFFFu) | (hi << 16));
            uv[d] = v;
        }
        bf16x8 B = __builtin_bit_cast(bf16x8, uv);
        acc[t] = __builtin_amdgcn_mfma_f32_16x16x32_bf16(s.a, B, acc[t], 0, 0, 0);
    }
}

template <int ISB>
__device__ void proj_body(const void* x, const void* wp, int arow,
                          size_t xb, int quad, floatx4 (&acc)[8])
{
    Stage s0, s1;
    ldstage<ISB>(x, xb, wp, arow, quad * 8, s0);
    #pragma unroll
    for (int q = 0; q < 8; q += 2) {
        ldstage<ISB>(x, xb, wp, arow, (q + 1) * 32 + quad * 8, s1);
        domfma(s0, acc);
        if (q + 2 < 8)
            ldstage<ISB>(x, xb, wp, arow, (q + 2) * 32 + quad * 8, s0);
        domfma(s1, acc);
    }
}

__global__ __launch_bounds__(192, 2) void proj_kernel(
    const void* __restrict__ x,
    const void* __restrict__ w1, const void* __restrict__ w2,
    const void* __restrict__ w3,
    const void* __restrict__ cpw, const void* __restrict__ cw1,
    const void* __restrict__ cw2,
    const void* __restrict__ b1g, const void* __restrict__ b1b,
    const void* __restrict__ b1m, const void* __restrict__ b1v,
    const void* __restrict__ b2g, const void* __restrict__ b2b,
    const void* __restrict__ b2m, const void* __restrict__ b2v,
    unsigned short* __restrict__ y12,
    unsigned short* __restrict__ y3a,
    float* __restrict__ prep)
{
    __shared__ int sflag;
    const int isb = detect_bf16(b1v, &sflag);
    const int tid = threadIdx.x;

    if (blockIdx.x == 0) {
        for (int i = tid; i < 4;   i += 192) prep[P_CP + i] = ldp(cpw, i, isb);
        for (int i = tid; i < 288; i += 192) prep[P_W1 + i] = ldp(cw1, i, isb);
        for (int i = tid; i < 128; i += 192) prep[P_W2 + i] = ldp(cw2, i, isb);
        if (tid == 0) prep[P_FLAG] = isb ? 1.f : 0.f;
        for (int i = tid; i < HW; i += 192) {
            float a1 = ldp(b1g, i, isb) * rsqrtf(ldp(b1v, i, isb) + 1e-3f);
            float c1 = ldp(b1b, i, isb) - ldp(b1m, i, isb) * a1;
            float a2 = ldp(b2g, i, isb) * rsqrtf(ldp(b2v, i, isb) + 1e-3f);
            float c2 = ldp(b2b, i, isb) - ldp(b2m, i, isb) * a2;
            prep[P_BN + i]          = a1;
            prep[P_BN + HW + i]     = c1;
            prep[P_BN + 2 * HW + i] = a2;
            prep[P_BN + 3 * HW + i] = c2;
        }
    }

    const int b   = blockIdx.x;
    const int n   = b / 50, r = b - n * 50;
    const int rh  = r / 25, pt = r - rh * 25;
    const int px0 = (pt < 24) ? pt * 128 : 3008;   // last block overlaps (benign dup)
    const int wv  = tid >> 6, lane = tid & 63;
    const int col = lane & 15, quad = lane >> 4;
    const int rt  = rh * 3 + wv;                   // row-tile 0..5 (16 rows each)

    const void* wp; int ro;
    if      (rt == 0) { wp = w1; ro = 0;  }
    else if (rt == 1) { wp = w2; ro = 0;  }
    else if (rt == 2) { wp = w3; ro = 0;  }
    else if (rt == 3) { wp = w3; ro = 16; }
    else if (rt == 4) { wp = w3; ro = 32; }
    else              { wp = w3; ro = 48; }

    const size_t xb = (size_t)n * 256 * HW + px0 + 8 * col;

    floatx4 acc[8] = {};
    if (isb) proj_body<1>(x, wp, ro + col, xb, quad, acc);
    else     proj_body<0>(x, wp, ro + col, xb, quad, acc);

    // D: ch = 16*rt + quad*4 + g, px = px0 + 8*col + t
    const int chq = quad * 4;
    #pragma unroll
    for (int t = 0; t < 8; ++t) {
        const int px = px0 + 8 * col + t;
        ushort4v pk;
        #pragma unroll
        for (int g = 0; g < 4; ++g) pk[g] = f2bf(acc[t][g]);
        if (rt < 2) {
            *(ushort4v*)(y12 + ((size_t)n * HW + px) * 32 + rt * 16 + chq) = pk;
        } else {
            const int k8 = 2 * (rt - 2) + (quad >> 1);
            *(ushort4v*)(y3a + (((size_t)n * 8 + k8) * HW + px) * 8 + (quad & 1) * 4) = pk;
        }
    }
}

// ---------------------------------------------------------------------------
// Fused attention: block = 576 threads (9 waves) = 64 pixels.
// Weights/BN via prep (uniform idx -> s_load). y12/y3a layouts coalesced.
// ---------------------------------------------------------------------------
__global__ __launch_bounds__(576) void attn_kernel(
    const unsigned short* __restrict__ y12,
    const unsigned short* __restrict__ y3a,
    const float* __restrict__ prep,
    void* __restrict__ out)
{
    __shared__ float wsm[64 * WS];
    const int tid = threadIdx.x;
    const int blk = blockIdx.x;
    const int n   = blk / 49;
    const int l0  = (blk - n * 49) * 64;
    const int isb = prep[P_FLAG] != 0.f;

    // ---- phase 1: pre-softmax h2[8] per (pixel, j) ----
    {
        const int j = tid >> 6;            // 0..8, wave-uniform
        const int p = tid & 63;
        const int l = l0 + p;
        const int h = l / 56, w = l - h * 56;
        const int dy = j / 3 - 1, dx = j - (j / 3) * 3 - 1;
        int hh = h + dy; hh = (hh < 0) ? -hh : ((hh > 55) ? 110 - hh : hh);
        int ww = w + dx; ww = (ww < 0) ? -ww : ((ww > 55) ? 110 - ww : ww);
        const int nbr = hh * 56 + ww;

        const float a1 = prep[P_BN + l];
        const float c1 = prep[P_BN + HW + l];
        const float a2 = prep[P_BN + 2 * HW + l];
        const float c2 = prep[P_BN + 3 * HW + l];

        const unsigned short* y1p = y12 + ((size_t)n * HW + l) * 32;
        const unsigned short* y2p = y12 + ((size_t)n * HW + nbr) * 32 + 16;
        float y1f[16], y2f[16];
        unp8(*(const uint4*)y1p, y1f);       unp8(*(const uint4*)(y1p + 8), y1f + 8);
        unp8(*(const uint4*)y2p, y2f);       unp8(*(const uint4*)(y2p + 8), y2f + 8);

        float rel[18];
        #pragma unroll
        for (int c = 0; c < 16; ++c)
            rel[c] = fmaxf(fmaf(y1f[c] - y2f[c], a1, c1), 0.f);
        const float dlw = (float)(w - ww) * (2.0f / 55.0f);
        const float dlh = (float)(h - hh) * (2.0f / 55.0f);
        rel[16] = fmaxf(fmaf(prep[P_CP + 0] * dlw + prep[P_CP + 1] * dlh, a1, c1), 0.f);
        rel[17] = fmaxf(fmaf(prep[P_CP + 2] * dlw + prep[P_CP + 3] * dlh, a1, c1), 0.f);

        float h1[16];
        #pragma unroll
        for (int o = 0; o < 16; ++o) {
            float s = 0.f;
            #pragma unroll
            for (int c = 0; c < 18; ++c)
                s = fmaf(prep[P_W1 + o * 18 + c], rel[c], s);
            h1[o] = fmaxf(fmaf(s, a2, c2), 0.f);
        }
        float h2[8];
        #pragma unroll
        for (int o2 = 0; o2 < 8; ++o2) {
            float s = 0.f;
            #pragma unroll
            for (int o = 0; o < 16; ++o)
                s = fmaf(prep[P_W2 + o2 * 16 + o], h1[o], s);
            h2[o2] = s;
        }
        float* wpt = &wsm[p * WS + j * 8];
        *(floatx4*)wpt       = *(floatx4*)&h2[0];
        *(floatx4*)(wpt + 4) = *(floatx4*)&h2[4];
    }
    __syncthreads();

    // ---- phase 2: softmax over j ----
    if (tid < 512) {
        const int c = tid & 7, p = tid >> 3;
        float v[9];
        #pragma unroll
        for (int j = 0; j < 9; ++j) v[j] = wsm[p * WS + j * 8 + c];
        float m = v[0];
        #pragma unroll
        for (int j = 1; j < 9; ++j) m = fmaxf(m, v[j]);
        float s = 0.f;
        #pragma unroll
        for (int j = 0; j < 9; ++j) { v[j] = __expf(v[j] - m); s += v[j]; }
        const float inv = 1.f / s;
        #pragma unroll
        for (int j = 0; j < 9; ++j) wsm[p * WS + j * 8 + c] = v[j] * inv;
    }
    __syncthreads();

    // ---- phase 3: aggregation, y3a reads 16 B/lane contiguous per wave ----
    if (tid < 512) {
        const int p  = tid & 63;
        const int k8 = tid >> 6;           // wave-uniform channel-group of 8
        const int l = l0 + p;
        const int h = l / 56, w = l - h * 56;
        int nbr[9];
        #pragma unroll
        for (int dy = 0; dy < 3; ++dy)
            #pragma unroll
            for (int dx = 0; dx < 3; ++dx) {
                int hh = h + dy - 1; hh = (hh < 0) ? -hh : ((hh > 55) ? 110 - hh : hh);
                int ww = w + dx - 1; ww = (ww < 0) ? -ww : ((ww > 55) ? 110 - ww : ww);
                nbr[dy * 3 + dx] = hh * 56 + ww;
            }
        const unsigned short* y3b = y3a + ((size_t)n * 8 + k8) * HW * 8;
        float acc8[8];
        #pragma unroll
        for (int k = 0; k < 8; ++k) acc8[k] = 0.f;
        #pragma unroll
        for (int j = 0; j < 9; ++j) {
            uint4 u = *(const uint4*)(y3b + (size_t)nbr[j] * 8);
            float yv[8];
            unp8(u, yv);
            const float* wpt = &wsm[p * WS + j * 8];
            #pragma unroll
            for (int k = 0; k < 8; ++k)
                acc8[k] = fmaf(wpt[k], yv[k], acc8[k]);
        }
        const size_t obase = ((size_t)n * 64 + k8 * 8) * HW + l;
        #pragma unroll
        for (int k = 0; k < 8; ++k) {
            if (isb) ((unsigned short*)out)[obase + (size_t)k * HW] = f2bf(acc8[k]);
            else     ((float*)out)[obase + (size_t)k * HW]          = acc8[k];
        }
    }
}

extern "C" void kernel_launch(void* const* d_in, const int* in_sizes, int n_in,
                              void* d_out, int out_size, void* d_ws, size_t ws_size,
                              hipStream_t stream)
{
    const size_t y12B = (size_t)16 * HW * 32 * 2;      // 3,211,264 B
    const size_t y3aB = (size_t)16 * 8 * HW * 8 * 2;   // 6,422,528 B

    unsigned short* y12 = (unsigned short*)d_ws;
    unsigned short* y3a = (unsigned short*)((char*)d_ws + y12B);
    float* prep = (float*)((char*)d_ws + y12B + y3aB);

    proj_kernel<<<dim3(800), dim3(192), 0, stream>>>(
        d_in[0], d_in[1], d_in[2], d_in[3],
        d_in[4], d_in[5], d_in[6],
        d_in[7], d_in[8], d_in[9], d_in[10],
        d_in[11], d_in[12], d_in[13], d_in[14],
        y12, y3a, prep);

    attn_kernel<<<dim3(784), dim3(576), 0, stream>>>(y12, y3a, prep, d_out);
}